// Round 10
// baseline (511.785 us; speedup 1.0000x reference)
//
#include <hip/hip_runtime.h>
#include <hip/hip_bf16.h>

#define NN 100000
#define NE 1600000
#define FD 128
#define NG 100
#define GFD 16
#define GHD 32

#define NB 391     // ceil(NN/256) buckets of 256 nodes
#define BCAP 5120  // per-bucket staging capacity

#define LROW 136   // padded LDS row (f16 elems): 2-way-max bank pattern

typedef __attribute__((ext_vector_type(8))) _Float16 f16x8;
typedef __attribute__((ext_vector_type(4))) float f32x4;

static inline int cdiv(int a, int b) { return (a + b - 1) / b; }

// ---------------- init: zero gcur + both sentinel rows ----------------
__global__ void k_init(int* __restrict__ gcur, _Float16* __restrict__ HsA,
                       _Float16* __restrict__ HsB) {
  int t = threadIdx.x;  // 512 threads, 1 block
  if (t < NB) gcur[t] = 0;
  if (t < FD) {
    HsA[(size_t)NN * FD + t] = (_Float16)0.f;
    HsB[(size_t)NN * FD + t] = (_Float16)0.f;
  }
}

// binA: bucket edges by dst>>8 into per-bucket staging, packed (src<<8)|(dst&255)
__global__ __launch_bounds__(256) void k_binA(const int* __restrict__ src,
                                              const int* __restrict__ dst,
                                              int* __restrict__ gcur,
                                              unsigned int* __restrict__ stag) {
  __shared__ int cnt[NB];
  __shared__ int gbase[NB];
  __shared__ int cursor[NB];
  int t = threadIdx.x;
  for (int i = t; i < NB; i += 256) cnt[i] = 0;
  __syncthreads();
  int e0 = blockIdx.x * 2048;
  int s[8], d[8], b[8];
#pragma unroll
  for (int j = 0; j < 8; j++) {
    int e = e0 + j * 256 + t;
    if (e < NE) {
      s[j] = src[e];
      d[j] = dst[e];
      b[j] = d[j] >> 8;
      atomicAdd(&cnt[b[j]], 1);
    } else {
      b[j] = -1;
    }
  }
  __syncthreads();
  for (int i = t; i < NB; i += 256) {
    int c = cnt[i];
    gbase[i] = (c > 0) ? atomicAdd(&gcur[i], c) : 0;
    cursor[i] = 0;
  }
  __syncthreads();
#pragma unroll
  for (int j = 0; j < 8; j++) {
    if (b[j] >= 0) {
      int r = atomicAdd(&cursor[b[j]], 1);
      stag[(size_t)b[j] * BCAP + gbase[b[j]] + r] =
          ((unsigned int)s[j] << 8) | (unsigned int)(d[j] & 255);
    }
  }
}

// binB: per-bucket degree histogram -> deg + dinv
__global__ __launch_bounds__(256) void k_binB(const unsigned int* __restrict__ stag,
                                              const int* __restrict__ gcur,
                                              int* __restrict__ deg,
                                              float* __restrict__ dinv) {
  __shared__ int h[256];
  int b = blockIdx.x;
  int t = threadIdx.x;
  h[t] = 0;
  __syncthreads();
  int n = gcur[b];
  const unsigned int* p = stag + (size_t)b * BCAP;
  for (int i = t; i < n; i += 256) atomicAdd(&h[p[i] & 255], 1);
  __syncthreads();
  int node = b * 256 + t;
  if (node < NN) {
    int dg = h[t];
    deg[node] = dg;
    dinv[node] = 1.0f / sqrtf((float)(dg + 1));
  }
}

// scan1 over PADDED degree (deg+7)&~7
__global__ __launch_bounds__(256) void k_scan1(const int* __restrict__ deg,
                                               int* __restrict__ offs,
                                               int* __restrict__ bsum) {
  __shared__ int sh[256];
  int b = blockIdx.x;
  int t = threadIdx.x;
  int base = b * 1024 + t * 4;
  int v0 = (base + 0 < NN) ? ((deg[base + 0] + 7) & ~7) : 0;
  int v1 = (base + 1 < NN) ? ((deg[base + 1] + 7) & ~7) : 0;
  int v2 = (base + 2 < NN) ? ((deg[base + 2] + 7) & ~7) : 0;
  int v3 = (base + 3 < NN) ? ((deg[base + 3] + 7) & ~7) : 0;
  int s = v0 + v1 + v2 + v3;
  sh[t] = s;
  __syncthreads();
  for (int off = 1; off < 256; off <<= 1) {
    int tv = (t >= off) ? sh[t - off] : 0;
    __syncthreads();
    sh[t] += tv;
    __syncthreads();
  }
  int excl = sh[t] - s;
  if (base + 0 < NN) offs[base + 0] = excl;
  if (base + 1 < NN) offs[base + 1] = excl + v0;
  if (base + 2 < NN) offs[base + 2] = excl + v0 + v1;
  if (base + 3 < NN) offs[base + 3] = excl + v0 + v1 + v2;
  if (t == 255) bsum[b] = sh[255];
}

__global__ __launch_bounds__(128) void k_scan2(int* __restrict__ bsum, int nb,
                                               int* __restrict__ ptot) {
  __shared__ int sh[128];
  int t = threadIdx.x;
  int v = (t < nb) ? bsum[t] : 0;
  sh[t] = v;
  __syncthreads();
  for (int off = 1; off < 128; off <<= 1) {
    int tv = (t >= off) ? sh[t - off] : 0;
    __syncthreads();
    sh[t] += tv;
    __syncthreads();
  }
  if (t < nb) bsum[t] = sh[t] - v;
  if (t == nb - 1) ptot[0] = sh[t];
}

// binC: finalize offs and place edges; pad with sentinel NN
__global__ __launch_bounds__(256) void k_binC(const unsigned int* __restrict__ stag,
                                              const int* __restrict__ gcur,
                                              const int* __restrict__ offsp,
                                              const int* __restrict__ bsum,
                                              const int* __restrict__ ptot,
                                              int* __restrict__ offs,
                                              int* __restrict__ ssrc) {
  __shared__ int cur[256];
  __shared__ int nxt[256];
  int b = blockIdx.x;
  int t = threadIdx.x;
  int node = b * 256 + t;
  int of = 0, ofn = 0;
  if (node < NN) {
    of = offsp[node] + bsum[node >> 10];
    ofn = (node + 1 < NN) ? (offsp[node + 1] + bsum[(node + 1) >> 10]) : ptot[0];
  }
  cur[t] = of;
  nxt[t] = ofn;
  __syncthreads();
  int n = gcur[b];
  const unsigned int* p = stag + (size_t)b * BCAP;
  for (int i = t; i < n; i += 256) {
    unsigned int v = p[i];
    int pos = atomicAdd(&cur[v & 255], 1);
    ssrc[pos] = (int)(v >> 8);
  }
  __syncthreads();
  if (node < NN) {
    offs[node] = of;
    if (node == NN - 1) offs[NN] = ptot[0];
    for (int pos = cur[t]; pos < nxt[t]; pos++) ssrc[pos] = NN;
  }
}

// ---------------- weight conversion (all 4 layers) ----------------
__global__ void k_cvt_w4(const float* __restrict__ W0, const float* __restrict__ W1,
                         const float* __restrict__ W2, const float* __restrict__ W3,
                         _Float16* __restrict__ Wf /* [4][32768] */) {
  int tt = blockIdx.x * blockDim.x + threadIdx.x;  // 0..65535
  int layer = tt >> 14;
  int t = tt & 16383;
  const float* W = (layer == 0) ? W0 : (layer == 1) ? W1 : (layer == 2) ? W2 : W3;
  int i = t & 7;
  int l = (t >> 3) & 63;
  int nt = (t >> 9) & 7;
  int kb = (t >> 12) & 3;
  int k = kb * 32 + (l >> 4) * 8 + i;
  int n = nt * 16 + (l & 15);
  float w = W[k * FD + n];
  _Float16 hi = (_Float16)w;
  _Float16* dst = Wf + (size_t)layer * 32768;
  dst[t] = hi;
  dst[t + 16384] = (_Float16)(w - (float)hi);
}

// ---------------- MFMA GEMM (fp32 input, layer 1) ----------------
__global__ __launch_bounds__(256) void k_gemm_mfma_f32(
    const float* __restrict__ X,
    const _Float16* __restrict__ Wfrag,
    const float* __restrict__ dinv,
    _Float16* __restrict__ Hs) {
  int tid = threadIdx.x;
  int lane = tid & 63;
  int wave = tid >> 6;
  int r0 = blockIdx.x * 64 + wave * 16;
  int arow = r0 + (lane & 15);
  int kgrp = lane >> 4;

  f32x4 acc[8];
#pragma unroll
  for (int nt = 0; nt < 8; nt++) acc[nt] = (f32x4){0.f, 0.f, 0.f, 0.f};

#pragma unroll
  for (int kb = 0; kb < 4; kb++) {
    f16x8 a;
    if (arow < NN) {
      const float4* xp = (const float4*)(X + (size_t)arow * FD + kb * 32 + kgrp * 8);
      float4 x0 = xp[0], x1 = xp[1];
      a = (f16x8){(_Float16)x0.x, (_Float16)x0.y, (_Float16)x0.z, (_Float16)x0.w,
                  (_Float16)x1.x, (_Float16)x1.y, (_Float16)x1.z, (_Float16)x1.w};
    } else {
      a = (f16x8){0, 0, 0, 0, 0, 0, 0, 0};
    }
    const _Float16* wp = Wfrag + ((size_t)(kb * 8) * 64 + lane) * 8;
#pragma unroll
    for (int nt = 0; nt < 8; nt++) {
      f16x8 bhi = *(const f16x8*)(wp + (size_t)nt * 64 * 8);
      f16x8 blo = *(const f16x8*)(wp + (size_t)nt * 64 * 8 + 16384);
      acc[nt] = __builtin_amdgcn_mfma_f32_16x16x32_f16(a, bhi, acc[nt], 0, 0, 0);
      acc[nt] = __builtin_amdgcn_mfma_f32_16x16x32_f16(a, blo, acc[nt], 0, 0, 0);
    }
  }

  int ccol = lane & 15;
  int rbase = r0 + (lane >> 4) * 4;
  float dv[4];
#pragma unroll
  for (int j = 0; j < 4; j++) dv[j] = (rbase + j < NN) ? dinv[rbase + j] : 0.f;
#pragma unroll
  for (int nt = 0; nt < 8; nt++) {
#pragma unroll
    for (int j = 0; j < 4; j++) {
      int r = rbase + j;
      if (r < NN) {
        Hs[(size_t)r * FD + nt * 16 + ccol] = (_Float16)(acc[nt][j] * dv[j]);
      }
    }
  }
}

// ---------------- FUSED: agg(layer l) -> LDS -> GEMM(layer l+1) ----------------
// Block = 64 nodes. Phase A: each wave aggregates 16 nodes (R6-style
// prefetch+bpermute, 16 edges/iter) and writes relu'd rows into LDS tile
// (padded rows). Phase B: MFMA GEMM reading A-fragments from LDS, N split in
// two halves to cap VGPR; writes Hs_out = (B @ W)*dinv only.
__global__ __launch_bounds__(256) void k_fused(
    const _Float16* __restrict__ HsIn,
    const float* __restrict__ dinv,
    const int* __restrict__ offs,
    const int* __restrict__ ssrc,
    const float* __restrict__ bias,
    const _Float16* __restrict__ Wfrag,
    _Float16* __restrict__ HsOut) {
  __shared__ _Float16 LB[64][LROW];
  int tid = threadIdx.x;
  int lane = tid & 63;
  int wave = tid >> 6;
  int g = lane >> 4;   // quadrant
  int c = lane & 15;   // 16B chunk of row

  // -------- phase A: aggregate 16 nodes per wave --------
  for (int i = 0; i < 16; i++) {
    int node = blockIdx.x * 64 + wave * 16 + i;
    int lrow = wave * 16 + i;
    if (node < NN) {
      int e0 = offs[node], e1 = offs[node + 1];
      int cnt = e1 - e0;  // multiple of 8
      int myidx = (lane < cnt) ? ssrc[e0 + lane] : NN;
      float acc[8];
#pragma unroll
      for (int k = 0; k < 8; k++) acc[k] = 0.f;
      for (int base = 0; base < cnt; base += 16) {
        int p = base + g * 4;
        int i0, i1, i2, i3;
        if (base < 64) {
          i0 = __builtin_amdgcn_ds_bpermute((p + 0) * 4, myidx);
          i1 = __builtin_amdgcn_ds_bpermute((p + 1) * 4, myidx);
          i2 = __builtin_amdgcn_ds_bpermute((p + 2) * 4, myidx);
          i3 = __builtin_amdgcn_ds_bpermute((p + 3) * 4, myidx);
        } else {
          i0 = (p + 0 < cnt) ? ssrc[e0 + p + 0] : NN;
          i1 = (p + 1 < cnt) ? ssrc[e0 + p + 1] : NN;
          i2 = (p + 2 < cnt) ? ssrc[e0 + p + 2] : NN;
          i3 = (p + 3 < cnt) ? ssrc[e0 + p + 3] : NN;
        }
        f16x8 v0 = *(const f16x8*)(HsIn + (size_t)i0 * FD + c * 8);
        f16x8 v1 = *(const f16x8*)(HsIn + (size_t)i1 * FD + c * 8);
        f16x8 v2 = *(const f16x8*)(HsIn + (size_t)i2 * FD + c * 8);
        f16x8 v3 = *(const f16x8*)(HsIn + (size_t)i3 * FD + c * 8);
#pragma unroll
        for (int k = 0; k < 8; k++) {
          acc[k] += ((float)v0[k] + (float)v1[k]) + ((float)v2[k] + (float)v3[k]);
        }
      }
#pragma unroll
      for (int k = 0; k < 8; k++) {
        acc[k] += __shfl_xor(acc[k], 16, 64);
        acc[k] += __shfl_xor(acc[k], 32, 64);
      }
      if (g == 0) {
        float di = dinv[node];
        f16x8 sf = *(const f16x8*)(HsIn + (size_t)node * FD + c * 8);
        float4 b0 = *(const float4*)(bias + c * 8);
        float4 b1 = *(const float4*)(bias + c * 8 + 4);
        float bb[8] = {b0.x, b0.y, b0.z, b0.w, b1.x, b1.y, b1.z, b1.w};
        f16x8 o;
#pragma unroll
        for (int k = 0; k < 8; k++) {
          o[k] = (_Float16)fmaxf(fmaf(acc[k] + (float)sf[k], di, bb[k]), 0.f);
        }
        *(f16x8*)(&LB[lrow][c * 8]) = o;
      }
    } else {
      if (g == 0) {
        f16x8 z = (f16x8){0, 0, 0, 0, 0, 0, 0, 0};
        *(f16x8*)(&LB[lrow][c * 8]) = z;
      }
    }
  }
  __syncthreads();

  // -------- phase B: GEMM from LDS, N in two halves --------
  int kgrp = lane >> 4;
  int arl = wave * 16 + (lane & 15);
  int ccol = lane & 15;
  int rbl = wave * 16 + (lane >> 4) * 4;
  int rglob = blockIdx.x * 64 + rbl;
  float dv[4];
#pragma unroll
  for (int j = 0; j < 4; j++) dv[j] = (rglob + j < NN) ? dinv[rglob + j] : 0.f;

#pragma unroll
  for (int half = 0; half < 2; half++) {
    f32x4 acc[4];
#pragma unroll
    for (int nt = 0; nt < 4; nt++) acc[nt] = (f32x4){0.f, 0.f, 0.f, 0.f};
#pragma unroll
    for (int kb = 0; kb < 4; kb++) {
      f16x8 a = *(const f16x8*)(&LB[arl][kb * 32 + kgrp * 8]);
#pragma unroll
      for (int nt = 0; nt < 4; nt++) {
        const _Float16* wp = Wfrag + ((size_t)(kb * 8 + half * 4 + nt) * 64 + lane) * 8;
        f16x8 bhi = *(const f16x8*)(wp);
        f16x8 blo = *(const f16x8*)(wp + 16384);
        acc[nt] = __builtin_amdgcn_mfma_f32_16x16x32_f16(a, bhi, acc[nt], 0, 0, 0);
        acc[nt] = __builtin_amdgcn_mfma_f32_16x16x32_f16(a, blo, acc[nt], 0, 0, 0);
      }
    }
#pragma unroll
    for (int nt = 0; nt < 4; nt++) {
#pragma unroll
      for (int j = 0; j < 4; j++) {
        int r = rglob + j;
        if (r < NN) {
          HsOut[(size_t)r * FD + (half * 4 + nt) * 16 + ccol] =
              (_Float16)(acc[nt][j] * dv[j]);
        }
      }
    }
  }
}

// ---------------- standalone aggregation (layer 4) ----------------
__global__ __launch_bounds__(256) void k_agg(const _Float16* __restrict__ Hs,
                                             const float* __restrict__ dinv,
                                             const int* __restrict__ offs,
                                             const int* __restrict__ ssrc,
                                             const float* __restrict__ bias,
                                             _Float16* __restrict__ Bout) {
  int wave = threadIdx.x >> 6;
  int lane = threadIdx.x & 63;
  int node = blockIdx.x * 4 + wave;  // grid exactly NN/4
  int g = lane >> 4;
  int c = lane & 15;

  int e0 = offs[node], e1 = offs[node + 1];
  int cnt = e1 - e0;
  int myidx = (lane < cnt) ? ssrc[e0 + lane] : NN;

  float acc[8];
#pragma unroll
  for (int k = 0; k < 8; k++) acc[k] = 0.f;

  for (int base = 0; base < cnt; base += 16) {
    int p = base + g * 4;
    int i0, i1, i2, i3;
    if (base < 64) {
      i0 = __builtin_amdgcn_ds_bpermute((p + 0) * 4, myidx);
      i1 = __builtin_amdgcn_ds_bpermute((p + 1) * 4, myidx);
      i2 = __builtin_amdgcn_ds_bpermute((p + 2) * 4, myidx);
      i3 = __builtin_amdgcn_ds_bpermute((p + 3) * 4, myidx);
    } else {
      i0 = (p + 0 < cnt) ? ssrc[e0 + p + 0] : NN;
      i1 = (p + 1 < cnt) ? ssrc[e0 + p + 1] : NN;
      i2 = (p + 2 < cnt) ? ssrc[e0 + p + 2] : NN;
      i3 = (p + 3 < cnt) ? ssrc[e0 + p + 3] : NN;
    }
    f16x8 v0 = *(const f16x8*)(Hs + (size_t)i0 * FD + c * 8);
    f16x8 v1 = *(const f16x8*)(Hs + (size_t)i1 * FD + c * 8);
    f16x8 v2 = *(const f16x8*)(Hs + (size_t)i2 * FD + c * 8);
    f16x8 v3 = *(const f16x8*)(Hs + (size_t)i3 * FD + c * 8);
#pragma unroll
    for (int k = 0; k < 8; k++) {
      acc[k] += ((float)v0[k] + (float)v1[k]) + ((float)v2[k] + (float)v3[k]);
    }
  }

#pragma unroll
  for (int k = 0; k < 8; k++) {
    acc[k] += __shfl_xor(acc[k], 16, 64);
    acc[k] += __shfl_xor(acc[k], 32, 64);
  }

  if (g == 0) {
    float di = dinv[node];
    f16x8 sf = *(const f16x8*)(Hs + (size_t)node * FD + c * 8);
    float4 b0 = *(const float4*)(bias + c * 8);
    float4 b1 = *(const float4*)(bias + c * 8 + 4);
    float bb[8] = {b0.x, b0.y, b0.z, b0.w, b1.x, b1.y, b1.z, b1.w};
    f16x8 o;
#pragma unroll
    for (int k = 0; k < 8; k++) {
      o[k] = (_Float16)fmaxf(fmaf(acc[k] + (float)sf[k], di, bb[k]), 0.f);
    }
    *(f16x8*)(Bout + (size_t)node * FD + c * 8) = o;
  }
}

// ---------------- pooling stage 1 ----------------
__global__ __launch_bounds__(128) void k_pool(const _Float16* __restrict__ H,
                                              const int* __restrict__ batch,
                                              float* __restrict__ part) {
  int g = blockIdx.x >> 3;
  int s = blockIdx.x & 7;
  int start, end;
  {
    int lo = 0, hi = NN;
    while (lo < hi) { int m = (lo + hi) >> 1; if (batch[m] < g) lo = m + 1; else hi = m; }
    start = lo;
    lo = start; hi = NN;
    while (lo < hi) { int m = (lo + hi) >> 1; if (batch[m] < g + 1) lo = m + 1; else hi = m; }
    end = lo;
  }
  int cnt = end - start;
  int chunk = (cnt + 7) >> 3;
  int a = start + s * chunk;
  int bnd = a + chunk;
  if (bnd > end) bnd = end;
  int f = threadIdx.x;
  float acc = 0.f;
  for (int i = a; i < bnd; i++) acc += (float)H[(size_t)i * FD + f];
  part[(size_t)blockIdx.x * FD + f] = acc;
}

// ---------------- tail MLP ----------------
__global__ __launch_bounds__(128) void k_tail(
    const float* __restrict__ part, const float* __restrict__ gfeats,
    const float* __restrict__ W1, const float* __restrict__ b1,
    const float* __restrict__ Wg, const float* __restrict__ bg,
    const float* __restrict__ W2, const float* __restrict__ b2,
    const float* __restrict__ W3, const float* __restrict__ b3,
    const float* __restrict__ W4, const float* __restrict__ b4,
    float* __restrict__ out) {
  __shared__ float row[FD];
  __shared__ float y1[FD];
  __shared__ float gv[GHD];
  __shared__ float y2[FD];
  __shared__ float red[FD];
  int g = blockIdx.x, j = threadIdx.x;

  float p = 0.f;
  for (int s = 0; s < 8; s++) p += part[(size_t)(g * 8 + s) * FD + j];
  row[j] = p;
  if (j < GHD) {
    float a = bg[j];
    for (int k = 0; k < GFD; k++) a = fmaf(gfeats[g * GFD + k], Wg[k * GHD + j], a);
    gv[j] = fmaxf(a, 0.f);
  }
  __syncthreads();

  float a1 = b1[j];
  for (int k = 0; k < FD; k++) a1 = fmaf(row[k], W1[k * FD + j], a1);
  y1[j] = fmaxf(a1, 0.f);
  __syncthreads();

  float a2 = b2[j];
  for (int k = 0; k < FD; k++) a2 = fmaf(y1[k], W2[k * FD + j], a2);
  for (int k = 0; k < GHD; k++) a2 = fmaf(gv[k], W2[(FD + k) * FD + j], a2);
  y2[j] = fmaxf(a2, 0.f);
  __syncthreads();

  float a3 = b3[j];
  for (int k = 0; k < FD; k++) a3 = fmaf(y2[k], W3[k * FD + j], a3);
  float y3 = fmaxf(a3, 0.f);

  red[j] = y3 * W4[j];
  __syncthreads();
  for (int st = 64; st > 0; st >>= 1) {
    if (j < st) red[j] += red[j + st];
    __syncthreads();
  }
  if (j == 0) out[g] = red[0] + b4[0];
}

// ---------------- launcher ----------------
extern "C" void kernel_launch(void* const* d_in, const int* in_sizes, int n_in,
                              void* d_out, int out_size, void* d_ws, size_t ws_size,
                              hipStream_t stream) {
  const float* x      = (const float*)d_in[0];
  const int*   ei     = (const int*)d_in[1];
  const int*   batch  = (const int*)d_in[2];
  const float* gfeats = (const float*)d_in[3];
  const float* c1W = (const float*)d_in[5];  const float* c1b = (const float*)d_in[6];
  const float* c2W = (const float*)d_in[7];  const float* c2b = (const float*)d_in[8];
  const float* c3W = (const float*)d_in[9];  const float* c3b = (const float*)d_in[10];
  const float* c4W = (const float*)d_in[11]; const float* c4b = (const float*)d_in[12];
  const float* gW  = (const float*)d_in[13]; const float* gb  = (const float*)d_in[14];
  const float* l1W = (const float*)d_in[15]; const float* l1b = (const float*)d_in[16];
  const float* l2W = (const float*)d_in[17]; const float* l2b = (const float*)d_in[18];
  const float* l3W = (const float*)d_in[19]; const float* l3b = (const float*)d_in[20];
  const float* l4W = (const float*)d_in[21]; const float* l4b = (const float*)d_in[22];
  const int* srcp = ei;
  const int* dstp = ei + NE;
  float* out = (float*)d_out;

  char* p = (char*)d_ws;
  auto alloc = [&](size_t bytes) {
    char* r = p;
    p += (bytes + 255) & ~(size_t)255;
    return (void*)r;
  };
  _Float16* HsA = (_Float16*)alloc((size_t)(NN + 1) * FD * 2);
  _Float16* HsB = (_Float16*)alloc((size_t)(NN + 1) * FD * 2);
  _Float16* Bb  = (_Float16*)alloc((size_t)NN * FD * 2);
  _Float16* Wf  = (_Float16*)alloc((size_t)4 * 32768 * 2);
  float* dinv = (float*)alloc((size_t)NN * 4);
  int*   deg  = (int*)alloc((size_t)NN * 4);
  int*   offs = (int*)alloc((size_t)(NN + 1) * 4);
  int*   ssrc = (int*)alloc((size_t)(NE + 8 * NN + 64) * 4);
  int*   bsum = (int*)alloc(128 * 4);
  int*   ptot = (int*)alloc(256);
  float* part = (float*)alloc((size_t)NG * 8 * FD * 4);
  unsigned int* stag = (unsigned int*)alloc((size_t)NB * BCAP * 4);  // 8 MB
  int*   gcur = (int*)alloc((size_t)NB * 4);

  int nb_scan = cdiv(NN, 1024);

  // CSR build (bucketed, padded)
  k_init<<<1, 512, 0, stream>>>(gcur, HsA, HsB);
  k_binA<<<cdiv(NE, 2048), 256, 0, stream>>>(srcp, dstp, gcur, stag);
  k_binB<<<NB, 256, 0, stream>>>(stag, gcur, deg, dinv);
  k_scan1<<<nb_scan, 256, 0, stream>>>(deg, offs, bsum);
  k_scan2<<<1, 128, 0, stream>>>(bsum, nb_scan, ptot);
  k_binC<<<NB, 256, 0, stream>>>(stag, gcur, offs, bsum, ptot, offs, ssrc);

  // weight conversions
  k_cvt_w4<<<256, 256, 0, stream>>>(c1W, c2W, c3W, c4W, Wf);

  // layers: gemm1, fused(agg1+gemm2), fused(agg2+gemm3), fused(agg3+gemm4), agg4
  int grid64 = cdiv(NN, 64);
  k_gemm_mfma_f32<<<grid64, 256, 0, stream>>>(x, Wf, dinv, HsA);
  k_fused<<<grid64, 256, 0, stream>>>(HsA, dinv, offs, ssrc, c1b,
                                      Wf + (size_t)1 * 32768, HsB);
  k_fused<<<grid64, 256, 0, stream>>>(HsB, dinv, offs, ssrc, c2b,
                                      Wf + (size_t)2 * 32768, HsA);
  k_fused<<<grid64, 256, 0, stream>>>(HsA, dinv, offs, ssrc, c3b,
                                      Wf + (size_t)3 * 32768, HsB);
  k_agg<<<NN / 4, 256, 0, stream>>>(HsB, dinv, offs, ssrc, c4b, Bb);

  // pooling + tail
  k_pool<<<NG * 8, 128, 0, stream>>>(Bb, batch, part);
  k_tail<<<NG, 128, 0, stream>>>(part, gfeats, l1W, l1b, gW, gb, l2W, l2b,
                                 l3W, l3b, l4W, l4b, out);
}

// Round 11
// 486.950 us; speedup vs baseline: 1.0510x; 1.0510x over previous
//
#include <hip/hip_runtime.h>
#include <hip/hip_bf16.h>

#define NN 100000
#define NE 1600000
#define FD 128
#define NG 100
#define GFD 16
#define GHD 32

#define NB 391     // ceil(NN/256) buckets of 256 nodes
#define BCAP 5120  // per-bucket staging capacity

typedef __attribute__((ext_vector_type(8))) _Float16 f16x8;
typedef __attribute__((ext_vector_type(4))) float f32x4;

static inline int cdiv(int a, int b) { return (a + b - 1) / b; }

// ---------------- init: zero gcur + sentinel row ----------------
__global__ void k_init(int* __restrict__ gcur, _Float16* __restrict__ Hs) {
  int t = threadIdx.x;  // 512 threads, 1 block
  if (t < NB) gcur[t] = 0;
  if (t < FD) Hs[(size_t)NN * FD + t] = (_Float16)0.f;
}

// binA: bucket edges by dst>>8 into per-bucket staging, packed (src<<8)|(dst&255)
__global__ __launch_bounds__(256) void k_binA(const int* __restrict__ src,
                                              const int* __restrict__ dst,
                                              int* __restrict__ gcur,
                                              unsigned int* __restrict__ stag) {
  __shared__ int cnt[NB];
  __shared__ int gbase[NB];
  __shared__ int cursor[NB];
  int t = threadIdx.x;
  for (int i = t; i < NB; i += 256) cnt[i] = 0;
  __syncthreads();
  int e0 = blockIdx.x * 2048;
  int s[8], d[8], b[8];
#pragma unroll
  for (int j = 0; j < 8; j++) {
    int e = e0 + j * 256 + t;
    if (e < NE) {
      s[j] = src[e];
      d[j] = dst[e];
      b[j] = d[j] >> 8;
      atomicAdd(&cnt[b[j]], 1);
    } else {
      b[j] = -1;
    }
  }
  __syncthreads();
  for (int i = t; i < NB; i += 256) {
    int c = cnt[i];
    gbase[i] = (c > 0) ? atomicAdd(&gcur[i], c) : 0;
    cursor[i] = 0;
  }
  __syncthreads();
#pragma unroll
  for (int j = 0; j < 8; j++) {
    if (b[j] >= 0) {
      int r = atomicAdd(&cursor[b[j]], 1);
      stag[(size_t)b[j] * BCAP + gbase[b[j]] + r] =
          ((unsigned int)s[j] << 8) | (unsigned int)(d[j] & 255);
    }
  }
}

// binB: per-bucket degree histogram -> dinv + in-bucket exclusive scan of
// PADDED degree ((d+7)&~7) -> offsp, bucket total -> bsum. (replaces scan1+deg)
__global__ __launch_bounds__(256) void k_binB(const unsigned int* __restrict__ stag,
                                              const int* __restrict__ gcur,
                                              float* __restrict__ dinv,
                                              int* __restrict__ offsp,
                                              int* __restrict__ bsum) {
  __shared__ int h[256];
  __shared__ int sh[256];
  int b = blockIdx.x;
  int t = threadIdx.x;
  h[t] = 0;
  __syncthreads();
  int n = gcur[b];
  const unsigned int* p = stag + (size_t)b * BCAP;
  for (int i = t; i < n; i += 256) atomicAdd(&h[p[i] & 255], 1);
  __syncthreads();
  int node = b * 256 + t;
  int dg = h[t];
  int pd = (node < NN) ? ((dg + 7) & ~7) : 0;
  if (node < NN) dinv[node] = 1.0f / sqrtf((float)(dg + 1));
  sh[t] = pd;
  __syncthreads();
  for (int off = 1; off < 256; off <<= 1) {
    int tv = (t >= off) ? sh[t - off] : 0;
    __syncthreads();
    sh[t] += tv;
    __syncthreads();
  }
  if (node < NN) offsp[node] = sh[t] - pd;
  if (t == 255) bsum[b] = sh[255];
}

// scan2: exclusive scan over 391 bucket totals (one 512-thread block)
__global__ __launch_bounds__(512) void k_scan2(int* __restrict__ bsum,
                                               int* __restrict__ ptot) {
  __shared__ int sh[512];
  int t = threadIdx.x;
  int v = (t < NB) ? bsum[t] : 0;
  sh[t] = v;
  __syncthreads();
  for (int off = 1; off < 512; off <<= 1) {
    int tv = (t >= off) ? sh[t - off] : 0;
    __syncthreads();
    sh[t] += tv;
    __syncthreads();
  }
  if (t < NB) bsum[t] = sh[t] - v;
  if (t == NB - 1) ptot[0] = sh[t];
}

// binC: finalize offs and place edges; pad with sentinel NN
__global__ __launch_bounds__(256) void k_binC(const unsigned int* __restrict__ stag,
                                              const int* __restrict__ gcur,
                                              const int* __restrict__ offsp,
                                              const int* __restrict__ bsum,
                                              const int* __restrict__ ptot,
                                              int* __restrict__ offs,
                                              int* __restrict__ ssrc) {
  __shared__ int cur[256];
  __shared__ int nxt[256];
  int b = blockIdx.x;
  int t = threadIdx.x;
  int node = b * 256 + t;
  int of = 0, ofn = 0;
  if (node < NN) {
    of = offsp[node] + bsum[node >> 8];
    ofn = (node + 1 < NN) ? (offsp[node + 1] + bsum[(node + 1) >> 8]) : ptot[0];
  }
  cur[t] = of;
  nxt[t] = ofn;
  __syncthreads();
  int n = gcur[b];
  const unsigned int* p = stag + (size_t)b * BCAP;
  for (int i = t; i < n; i += 256) {
    unsigned int v = p[i];
    int pos = atomicAdd(&cur[v & 255], 1);
    ssrc[pos] = (int)(v >> 8);
  }
  __syncthreads();
  if (node < NN) {
    offs[node] = of;
    if (node == NN - 1) offs[NN] = ptot[0];
    for (int pos = cur[t]; pos < nxt[t]; pos++) ssrc[pos] = NN;
  }
}

// ---------------- weight conversion (all 4 layers) ----------------
__global__ void k_cvt_w4(const float* __restrict__ W0, const float* __restrict__ W1,
                         const float* __restrict__ W2, const float* __restrict__ W3,
                         _Float16* __restrict__ Wf /* [4][32768] */) {
  int tt = blockIdx.x * blockDim.x + threadIdx.x;  // 0..65535
  int layer = tt >> 14;
  int t = tt & 16383;
  const float* W = (layer == 0) ? W0 : (layer == 1) ? W1 : (layer == 2) ? W2 : W3;
  int i = t & 7;
  int l = (t >> 3) & 63;
  int nt = (t >> 9) & 7;
  int kb = (t >> 12) & 3;
  int k = kb * 32 + (l >> 4) * 8 + i;
  int n = nt * 16 + (l & 15);
  float w = W[k * FD + n];
  _Float16 hi = (_Float16)w;
  _Float16* dst = Wf + (size_t)layer * 32768;
  dst[t] = hi;
  dst[t + 16384] = (_Float16)(w - (float)hi);
}

// ---------------- MFMA GEMM (fp16 input, dense): Hs = fp16((Xh@W)*dinv) ----------------
__global__ __launch_bounds__(256) void k_gemm_mfma(
    const _Float16* __restrict__ Xh,
    const _Float16* __restrict__ Wfrag,
    const float* __restrict__ dinv,
    _Float16* __restrict__ Hs) {
  int tid = threadIdx.x;
  int lane = tid & 63;
  int wave = tid >> 6;
  int r0 = blockIdx.x * 64 + wave * 16;
  int arow = r0 + (lane & 15);
  int kgrp = lane >> 4;

  f32x4 acc[8];
#pragma unroll
  for (int nt = 0; nt < 8; nt++) acc[nt] = (f32x4){0.f, 0.f, 0.f, 0.f};

#pragma unroll
  for (int kb = 0; kb < 4; kb++) {
    f16x8 a;
    if (arow < NN) {
      a = *(const f16x8*)(Xh + (size_t)arow * FD + kb * 32 + kgrp * 8);
    } else {
      a = (f16x8){0, 0, 0, 0, 0, 0, 0, 0};
    }
    const _Float16* wp = Wfrag + ((size_t)(kb * 8) * 64 + lane) * 8;
#pragma unroll
    for (int nt = 0; nt < 8; nt++) {
      f16x8 bhi = *(const f16x8*)(wp + (size_t)nt * 64 * 8);
      f16x8 blo = *(const f16x8*)(wp + (size_t)nt * 64 * 8 + 16384);
      acc[nt] = __builtin_amdgcn_mfma_f32_16x16x32_f16(a, bhi, acc[nt], 0, 0, 0);
      acc[nt] = __builtin_amdgcn_mfma_f32_16x16x32_f16(a, blo, acc[nt], 0, 0, 0);
    }
  }

  int ccol = lane & 15;
  int rbase = r0 + (lane >> 4) * 4;
  float dv[4];
#pragma unroll
  for (int j = 0; j < 4; j++) dv[j] = (rbase + j < NN) ? dinv[rbase + j] : 0.f;
#pragma unroll
  for (int nt = 0; nt < 8; nt++) {
#pragma unroll
    for (int j = 0; j < 4; j++) {
      int r = rbase + j;
      if (r < NN) {
        Hs[(size_t)r * FD + nt * 16 + ccol] = (_Float16)(acc[nt][j] * dv[j]);
      }
    }
  }
}

// ---------------- MFMA GEMM (fp32 input, layer 1) ----------------
__global__ __launch_bounds__(256) void k_gemm_mfma_f32(
    const float* __restrict__ X,
    const _Float16* __restrict__ Wfrag,
    const float* __restrict__ dinv,
    _Float16* __restrict__ Hs) {
  int tid = threadIdx.x;
  int lane = tid & 63;
  int wave = tid >> 6;
  int r0 = blockIdx.x * 64 + wave * 16;
  int arow = r0 + (lane & 15);
  int kgrp = lane >> 4;

  f32x4 acc[8];
#pragma unroll
  for (int nt = 0; nt < 8; nt++) acc[nt] = (f32x4){0.f, 0.f, 0.f, 0.f};

#pragma unroll
  for (int kb = 0; kb < 4; kb++) {
    f16x8 a;
    if (arow < NN) {
      const float4* xp = (const float4*)(X + (size_t)arow * FD + kb * 32 + kgrp * 8);
      float4 x0 = xp[0], x1 = xp[1];
      a = (f16x8){(_Float16)x0.x, (_Float16)x0.y, (_Float16)x0.z, (_Float16)x0.w,
                  (_Float16)x1.x, (_Float16)x1.y, (_Float16)x1.z, (_Float16)x1.w};
    } else {
      a = (f16x8){0, 0, 0, 0, 0, 0, 0, 0};
    }
    const _Float16* wp = Wfrag + ((size_t)(kb * 8) * 64 + lane) * 8;
#pragma unroll
    for (int nt = 0; nt < 8; nt++) {
      f16x8 bhi = *(const f16x8*)(wp + (size_t)nt * 64 * 8);
      f16x8 blo = *(const f16x8*)(wp + (size_t)nt * 64 * 8 + 16384);
      acc[nt] = __builtin_amdgcn_mfma_f32_16x16x32_f16(a, bhi, acc[nt], 0, 0, 0);
      acc[nt] = __builtin_amdgcn_mfma_f32_16x16x32_f16(a, blo, acc[nt], 0, 0, 0);
    }
  }

  int ccol = lane & 15;
  int rbase = r0 + (lane >> 4) * 4;
  float dv[4];
#pragma unroll
  for (int j = 0; j < 4; j++) dv[j] = (rbase + j < NN) ? dinv[rbase + j] : 0.f;
#pragma unroll
  for (int nt = 0; nt < 8; nt++) {
#pragma unroll
    for (int j = 0; j < 4; j++) {
      int r = rbase + j;
      if (r < NN) {
        Hs[(size_t)r * FD + nt * 16 + ccol] = (_Float16)(acc[nt][j] * dv[j]);
      }
    }
  }
}

// ---------------- aggregation + bias + relu (R6 best variant) ----------------
// One wave per node; indices preloaded coalesced, per-iter via ds_bpermute;
// 16 edges (4 gathers of 4 rows) per iteration; sentinel row NN zeros.
__global__ __launch_bounds__(256) void k_agg(const _Float16* __restrict__ Hs,
                                             const float* __restrict__ dinv,
                                             const int* __restrict__ offs,
                                             const int* __restrict__ ssrc,
                                             const float* __restrict__ bias,
                                             _Float16* __restrict__ Bout) {
  int wave = threadIdx.x >> 6;
  int lane = threadIdx.x & 63;
  int node = blockIdx.x * 4 + wave;  // grid exactly NN/4
  int g = lane >> 4;                 // 0..3 quadrant
  int c = lane & 15;                 // 16B chunk of the row

  int e0 = offs[node], e1 = offs[node + 1];
  int cnt = e1 - e0;  // multiple of 8
  int myidx = (lane < cnt) ? ssrc[e0 + lane] : NN;

  float acc[8];
#pragma unroll
  for (int k = 0; k < 8; k++) acc[k] = 0.f;

  for (int base = 0; base < cnt; base += 16) {
    int p = base + g * 4;
    int i0, i1, i2, i3;
    if (base < 64) {  // wave-uniform; covers all realistic degrees
      i0 = __builtin_amdgcn_ds_bpermute((p + 0) * 4, myidx);
      i1 = __builtin_amdgcn_ds_bpermute((p + 1) * 4, myidx);
      i2 = __builtin_amdgcn_ds_bpermute((p + 2) * 4, myidx);
      i3 = __builtin_amdgcn_ds_bpermute((p + 3) * 4, myidx);
    } else {  // fallback for extreme degree
      i0 = (p + 0 < cnt) ? ssrc[e0 + p + 0] : NN;
      i1 = (p + 1 < cnt) ? ssrc[e0 + p + 1] : NN;
      i2 = (p + 2 < cnt) ? ssrc[e0 + p + 2] : NN;
      i3 = (p + 3 < cnt) ? ssrc[e0 + p + 3] : NN;
    }
    f16x8 v0 = *(const f16x8*)(Hs + (size_t)i0 * FD + c * 8);
    f16x8 v1 = *(const f16x8*)(Hs + (size_t)i1 * FD + c * 8);
    f16x8 v2 = *(const f16x8*)(Hs + (size_t)i2 * FD + c * 8);
    f16x8 v3 = *(const f16x8*)(Hs + (size_t)i3 * FD + c * 8);
#pragma unroll
    for (int k = 0; k < 8; k++) {
      acc[k] += ((float)v0[k] + (float)v1[k]) + ((float)v2[k] + (float)v3[k]);
    }
  }

#pragma unroll
  for (int k = 0; k < 8; k++) {
    acc[k] += __shfl_xor(acc[k], 16, 64);
    acc[k] += __shfl_xor(acc[k], 32, 64);
  }

  if (g == 0) {
    float di = dinv[node];
    f16x8 sf = *(const f16x8*)(Hs + (size_t)node * FD + c * 8);
    float4 b0 = *(const float4*)(bias + c * 8);
    float4 b1 = *(const float4*)(bias + c * 8 + 4);
    float bb[8] = {b0.x, b0.y, b0.z, b0.w, b1.x, b1.y, b1.z, b1.w};
    f16x8 o;
#pragma unroll
    for (int k = 0; k < 8; k++) {
      o[k] = (_Float16)fmaxf(fmaf(acc[k] + (float)sf[k], di, bb[k]), 0.f);
    }
    *(f16x8*)(Bout + (size_t)node * FD + c * 8) = o;
  }
}

// ---------------- pooling stage 1 ----------------
__global__ __launch_bounds__(128) void k_pool(const _Float16* __restrict__ H,
                                              const int* __restrict__ batch,
                                              float* __restrict__ part) {
  int g = blockIdx.x >> 3;
  int s = blockIdx.x & 7;
  int start, end;
  {
    int lo = 0, hi = NN;
    while (lo < hi) { int m = (lo + hi) >> 1; if (batch[m] < g) lo = m + 1; else hi = m; }
    start = lo;
    lo = start; hi = NN;
    while (lo < hi) { int m = (lo + hi) >> 1; if (batch[m] < g + 1) lo = m + 1; else hi = m; }
    end = lo;
  }
  int cnt = end - start;
  int chunk = (cnt + 7) >> 3;
  int a = start + s * chunk;
  int bnd = a + chunk;
  if (bnd > end) bnd = end;
  int f = threadIdx.x;
  float acc = 0.f;
  for (int i = a; i < bnd; i++) acc += (float)H[(size_t)i * FD + f];
  part[(size_t)blockIdx.x * FD + f] = acc;
}

// ---------------- tail MLP ----------------
__global__ __launch_bounds__(128) void k_tail(
    const float* __restrict__ part, const float* __restrict__ gfeats,
    const float* __restrict__ W1, const float* __restrict__ b1,
    const float* __restrict__ Wg, const float* __restrict__ bg,
    const float* __restrict__ W2, const float* __restrict__ b2,
    const float* __restrict__ W3, const float* __restrict__ b3,
    const float* __restrict__ W4, const float* __restrict__ b4,
    float* __restrict__ out) {
  __shared__ float row[FD];
  __shared__ float y1[FD];
  __shared__ float gv[GHD];
  __shared__ float y2[FD];
  __shared__ float red[FD];
  int g = blockIdx.x, j = threadIdx.x;

  float p = 0.f;
  for (int s = 0; s < 8; s++) p += part[(size_t)(g * 8 + s) * FD + j];
  row[j] = p;
  if (j < GHD) {
    float a = bg[j];
    for (int k = 0; k < GFD; k++) a = fmaf(gfeats[g * GFD + k], Wg[k * GHD + j], a);
    gv[j] = fmaxf(a, 0.f);
  }
  __syncthreads();

  float a1 = b1[j];
  for (int k = 0; k < FD; k++) a1 = fmaf(row[k], W1[k * FD + j], a1);
  y1[j] = fmaxf(a1, 0.f);
  __syncthreads();

  float a2 = b2[j];
  for (int k = 0; k < FD; k++) a2 = fmaf(y1[k], W2[k * FD + j], a2);
  for (int k = 0; k < GHD; k++) a2 = fmaf(gv[k], W2[(FD + k) * FD + j], a2);
  y2[j] = fmaxf(a2, 0.f);
  __syncthreads();

  float a3 = b3[j];
  for (int k = 0; k < FD; k++) a3 = fmaf(y2[k], W3[k * FD + j], a3);
  float y3 = fmaxf(a3, 0.f);

  red[j] = y3 * W4[j];
  __syncthreads();
  for (int st = 64; st > 0; st >>= 1) {
    if (j < st) red[j] += red[j + st];
    __syncthreads();
  }
  if (j == 0) out[g] = red[0] + b4[0];
}

// ---------------- launcher ----------------
extern "C" void kernel_launch(void* const* d_in, const int* in_sizes, int n_in,
                              void* d_out, int out_size, void* d_ws, size_t ws_size,
                              hipStream_t stream) {
  const float* x      = (const float*)d_in[0];
  const int*   ei     = (const int*)d_in[1];
  const int*   batch  = (const int*)d_in[2];
  const float* gfeats = (const float*)d_in[3];
  const float* c1W = (const float*)d_in[5];  const float* c1b = (const float*)d_in[6];
  const float* c2W = (const float*)d_in[7];  const float* c2b = (const float*)d_in[8];
  const float* c3W = (const float*)d_in[9];  const float* c3b = (const float*)d_in[10];
  const float* c4W = (const float*)d_in[11]; const float* c4b = (const float*)d_in[12];
  const float* gW  = (const float*)d_in[13]; const float* gb  = (const float*)d_in[14];
  const float* l1W = (const float*)d_in[15]; const float* l1b = (const float*)d_in[16];
  const float* l2W = (const float*)d_in[17]; const float* l2b = (const float*)d_in[18];
  const float* l3W = (const float*)d_in[19]; const float* l3b = (const float*)d_in[20];
  const float* l4W = (const float*)d_in[21]; const float* l4b = (const float*)d_in[22];
  const int* srcp = ei;
  const int* dstp = ei + NE;
  float* out = (float*)d_out;

  char* p = (char*)d_ws;
  auto alloc = [&](size_t bytes) {
    char* r = p;
    p += (bytes + 255) & ~(size_t)255;
    return (void*)r;
  };
  _Float16* Hs  = (_Float16*)alloc((size_t)(NN + 1) * FD * 2);  // +1 sentinel zero row
  _Float16* Bb  = (_Float16*)alloc((size_t)NN * FD * 2);
  _Float16* Wf  = (_Float16*)alloc((size_t)4 * 32768 * 2);
  float* dinv = (float*)alloc((size_t)NN * 4);
  int*   offsp = (int*)alloc((size_t)NN * 4);
  int*   offs = (int*)alloc((size_t)(NN + 1) * 4);
  int*   ssrc = (int*)alloc((size_t)(NE + 8 * NN + 64) * 4);  // padded CSR + slack
  int*   bsum = (int*)alloc(512 * 4);
  int*   ptot = (int*)alloc(256);
  float* part = (float*)alloc((size_t)NG * 8 * FD * 4);
  unsigned int* stag = (unsigned int*)alloc((size_t)NB * BCAP * 4);  // 8 MB
  int*   gcur = (int*)alloc((size_t)NB * 4);

  // CSR build (bucketed, padded)
  k_init<<<1, 512, 0, stream>>>(gcur, Hs);
  k_binA<<<cdiv(NE, 2048), 256, 0, stream>>>(srcp, dstp, gcur, stag);
  k_binB<<<NB, 256, 0, stream>>>(stag, gcur, dinv, offsp, bsum);
  k_scan2<<<1, 512, 0, stream>>>(bsum, ptot);
  k_binC<<<NB, 256, 0, stream>>>(stag, gcur, offsp, bsum, ptot, offs, ssrc);

  // weight conversions (one launch for all 4 layers)
  k_cvt_w4<<<256, 256, 0, stream>>>(c1W, c2W, c3W, c4W, Wf);

  // 4 GCN layers
  int gemm_grid = cdiv(NN, 64);
  const float* bs4[4] = {c1b, c2b, c3b, c4b};
  k_gemm_mfma_f32<<<gemm_grid, 256, 0, stream>>>(x, Wf, dinv, Hs);
  k_agg<<<NN / 4, 256, 0, stream>>>(Hs, dinv, offs, ssrc, bs4[0], Bb);
  for (int l = 1; l < 4; l++) {
    k_gemm_mfma<<<gemm_grid, 256, 0, stream>>>(Bb, Wf + (size_t)l * 32768, dinv, Hs);
    k_agg<<<NN / 4, 256, 0, stream>>>(Hs, dinv, offs, ssrc, bs4[l], Bb);
  }

  // pooling + tail
  k_pool<<<NG * 8, 128, 0, stream>>>(Bb, batch, part);
  k_tail<<<NG, 128, 0, stream>>>(part, gfeats, l1W, l1b, gW, gb, l2W, l2b,
                                 l3W, l3b, l4W, l4b, out);
}